// Round 1
// baseline (93.667 us; speedup 1.0000x reference)
//
#include <hip/hip_runtime.h>
#include <math.h>

// Problem geometry (fixed by reference):
//   x: (4, 256, 256) f32, q_params: (8,) f32, w_comb: (256,256) f32, b_comb: (256,) f32
//   out: (4, 256, 256) f32
// heads = 32, head_dim = 8, seq = 256, batch = 4.
//
// Quantum layer collapses analytically (see round notes):
//   g_j = cos(x[...,j] + p_j);  q[0] = g1*...*g7;  q[w>=1] = g0*...*gw

#define BATCH 4
#define SEQ   256
#define EMB   256
#define HEADS 32
#define HD    8

// ---------------------------------------------------------------------------
// Kernel 1: per-(batch,head) fused q-compute + attention (online softmax).
// grid = 128 blocks (b*32+h), block = 256 threads (one query row each).
// ---------------------------------------------------------------------------
__global__ __launch_bounds__(256) void qattn_kernel(
    const float* __restrict__ x,
    const float* __restrict__ qp,
    float* __restrict__ att)   // (4*256, 256) row-major, layout [b][s][h*8+d]
{
    const int bh = blockIdx.x;        // 0..127
    const int b  = bh >> 5;
    const int h  = bh & 31;
    const int t  = threadIdx.x;       // query row / key row index

    __shared__ float q_lds[SEQ][HD];  // 8 KiB; reads are uniform-address (broadcast)

    // --- compute this thread's q row from the collapsed circuit ---
    const float* xr = x + ((size_t)(b * SEQ + t) * EMB + h * HD);
    float g[HD];
#pragma unroll
    for (int j = 0; j < HD; ++j) g[j] = cosf(xr[j] + qp[j]);

    float qr[HD];
    {
        float run = g[0];
#pragma unroll
        for (int j = 1; j < HD; ++j) { run *= g[j]; qr[j] = run; }
        float s0 = g[1];
#pragma unroll
        for (int j = 2; j < HD; ++j) s0 *= g[j];
        qr[0] = s0;
    }

    *reinterpret_cast<float4*>(&q_lds[t][0]) = make_float4(qr[0], qr[1], qr[2], qr[3]);
    *reinterpret_cast<float4*>(&q_lds[t][4]) = make_float4(qr[4], qr[5], qr[6], qr[7]);
    __syncthreads();

    // --- online-softmax attention over the 256 key rows ---
    const float scale = 0.35355339059327373f;  // 1/sqrt(8)
    float m = -3.0e38f, l = 0.0f;
    float a0 = 0.f, a1 = 0.f, a2 = 0.f, a3 = 0.f,
          a4 = 0.f, a5 = 0.f, a6 = 0.f, a7 = 0.f;

    for (int k = 0; k < SEQ; ++k) {
        float4 kv0 = *reinterpret_cast<const float4*>(&q_lds[k][0]);
        float4 kv1 = *reinterpret_cast<const float4*>(&q_lds[k][4]);
        float dot = qr[0] * kv0.x + qr[1] * kv0.y + qr[2] * kv0.z + qr[3] * kv0.w
                  + qr[4] * kv1.x + qr[5] * kv1.y + qr[6] * kv1.z + qr[7] * kv1.w;
        float s  = dot * scale;
        float mn = fmaxf(m, s);
        float corr = __expf(m - mn);   // first iter: exp(-huge) == 0
        float pv   = __expf(s - mn);
        l = l * corr + pv;
        a0 = a0 * corr + pv * kv0.x;
        a1 = a1 * corr + pv * kv0.y;
        a2 = a2 * corr + pv * kv0.z;
        a3 = a3 * corr + pv * kv0.w;
        a4 = a4 * corr + pv * kv1.x;
        a5 = a5 * corr + pv * kv1.y;
        a6 = a6 * corr + pv * kv1.z;
        a7 = a7 * corr + pv * kv1.w;
        m = mn;
    }

    const float inv = 1.0f / l;
    float* yr = att + ((size_t)(b * SEQ + t) * EMB + h * HD);
    *reinterpret_cast<float4*>(&yr[0]) = make_float4(a0 * inv, a1 * inv, a2 * inv, a3 * inv);
    *reinterpret_cast<float4*>(&yr[4]) = make_float4(a4 * inv, a5 * inv, a6 * inv, a7 * inv);
}

// ---------------------------------------------------------------------------
// Kernel 2: Y = A @ W^T + bias.  A: (1024,256), W: (256,256) row-major [n][k].
// BM=32, BN=64, BK=32; 256 threads; each thread computes 2x4 outputs.
// grid = (1024/32, 256/64) = (32, 4) = 128 blocks.
// ---------------------------------------------------------------------------
#define BM 32
#define BN 64
#define BK 32

__global__ __launch_bounds__(256) void comb_kernel(
    const float* __restrict__ A,
    const float* __restrict__ W,
    const float* __restrict__ bias,
    float* __restrict__ Y)
{
    const int tid = threadIdx.x;
    const int tx  = tid & 15;   // N: 16 groups of 4 cols
    const int ty  = tid >> 4;   // M: 16 groups of 2 rows

    const int row0 = blockIdx.x * BM;
    const int col0 = blockIdx.y * BN;

    __shared__ float As[BM][BK + 1];
    __shared__ float Ws[BN][BK + 1];

    float acc[2][4] = {};

    for (int k0 = 0; k0 < EMB; k0 += BK) {
        {   // A tile: 32x32 floats -> 1 float4 per thread
            int r = tid >> 3, c4 = (tid & 7) * 4;
            float4 v = *reinterpret_cast<const float4*>(&A[(size_t)(row0 + r) * EMB + k0 + c4]);
            As[r][c4 + 0] = v.x; As[r][c4 + 1] = v.y;
            As[r][c4 + 2] = v.z; As[r][c4 + 3] = v.w;
        }
#pragma unroll
        for (int i = 0; i < 2; ++i) {  // W tile: 64x32 floats -> 2 float4 per thread
            int idx = tid + i * 256;
            int r = idx >> 3, c4 = (idx & 7) * 4;
            float4 v = *reinterpret_cast<const float4*>(&W[(size_t)(col0 + r) * EMB + k0 + c4]);
            Ws[r][c4 + 0] = v.x; Ws[r][c4 + 1] = v.y;
            Ws[r][c4 + 2] = v.z; Ws[r][c4 + 3] = v.w;
        }
        __syncthreads();

#pragma unroll
        for (int k = 0; k < BK; ++k) {
            float av0 = As[ty * 2 + 0][k];
            float av1 = As[ty * 2 + 1][k];
            float w0 = Ws[tx * 4 + 0][k];
            float w1 = Ws[tx * 4 + 1][k];
            float w2 = Ws[tx * 4 + 2][k];
            float w3 = Ws[tx * 4 + 3][k];
            acc[0][0] += av0 * w0; acc[0][1] += av0 * w1;
            acc[0][2] += av0 * w2; acc[0][3] += av0 * w3;
            acc[1][0] += av1 * w0; acc[1][1] += av1 * w1;
            acc[1][2] += av1 * w2; acc[1][3] += av1 * w3;
        }
        __syncthreads();
    }

    const int colb = col0 + tx * 4;
    float4 bv = *reinterpret_cast<const float4*>(&bias[colb]);
#pragma unroll
    for (int r = 0; r < 2; ++r) {
        int row = row0 + ty * 2 + r;
        float4 o = make_float4(acc[r][0] + bv.x, acc[r][1] + bv.y,
                               acc[r][2] + bv.z, acc[r][3] + bv.w);
        *reinterpret_cast<float4*>(&Y[(size_t)row * EMB + colb]) = o;
    }
}

extern "C" void kernel_launch(void* const* d_in, const int* in_sizes, int n_in,
                              void* d_out, int out_size, void* d_ws, size_t ws_size,
                              hipStream_t stream) {
    const float* x    = (const float*)d_in[0];   // 4*256*256
    const float* qp   = (const float*)d_in[1];   // 8
    const float* w    = (const float*)d_in[2];   // 256*256
    const float* bias = (const float*)d_in[3];   // 256
    float* out = (float*)d_out;                  // 4*256*256
    float* att = (float*)d_ws;                   // needs 1 MiB scratch (fully rewritten each call)

    qattn_kernel<<<BATCH * HEADS, 256, 0, stream>>>(x, qp, att);
    comb_kernel<<<dim3((BATCH * SEQ) / BM, EMB / BN), 256, 0, stream>>>(att, w, bias, out);
}

// Round 4
// 79.032 us; speedup vs baseline: 1.1852x; 1.1852x over previous
//
#include <hip/hip_runtime.h>
#include <math.h>

// Geometry (fixed): x (4,256,256) f32, q_params (8,) f32, w_comb (256,256) f32,
// b_comb (256,) f32 -> out (4,256,256) f32. heads=32, hd=8, seq=256, batch=4.
//
// Quantum layer collapses analytically:
//   g_j = cos(x_j + p_j);  q[0] = g1*...*g7;  q[w>=1] = g0*...*gw
//
// Softmax note: |q_d| <= 1 => |score| <= 8/sqrt(8) = 2.83, exp(s) <= 17,
// denom <= 256*17 — fp32-safe WITHOUT max subtraction. So no online-softmax
// rescale chain; partial (l, acc[8]) sums combine additively across k-splits.

#define BATCH 4
#define SEQ   256
#define EMB   256
#define HEADS 32
#define HD    8

// ---------------------------------------------------------------------------
// Kernel 1: fused q-compute + attention.
// grid = 256 blocks: blockIdx.x = (b*32+h)*2 + qhalf   (1 block/CU)
// block = 256 threads = 4 waves: thread t -> q-row (qhalf*128 + (t&127)),
// key-half (t>>7). Each thread loops 128 keys; partials combined in LDS.
// All inner-loop LDS reads are wave-broadcast (kk uniform, khalf wave-uniform)
// => conflict-free.
// ---------------------------------------------------------------------------
__global__ __launch_bounds__(256) void qattn_kernel(
    const float* __restrict__ x,
    const float* __restrict__ qp,
    float* __restrict__ att)   // (4*256, 256) layout [b][s][h*8+d]
{
    const int blk   = blockIdx.x;
    const int qhalf = blk & 1;
    const int bh    = blk >> 1;
    const int b     = bh >> 5;
    const int h     = bh & 31;
    const int t     = threadIdx.x;   // 0..255
    const int r     = t & 127;       // q-row within half
    const int khalf = t >> 7;

    __shared__ float k_lds[SEQ][HD];     // 8 KiB, all 256 collapsed rows
    __shared__ float p_lds[128][10];     // khalf=1 partials (l, acc[8]), 5 KiB

    // ---- compute collapsed-circuit row t into LDS ----
    {
        const float* xr = x + ((size_t)(b * SEQ + t) * EMB + h * HD);
        float g[HD];
#pragma unroll
        for (int j = 0; j < HD; ++j) g[j] = cosf(xr[j] + qp[j]);
        float kv[HD];
        float run = g[0];
#pragma unroll
        for (int j = 1; j < HD; ++j) { run *= g[j]; kv[j] = run; }
        float s0 = g[1];
#pragma unroll
        for (int j = 2; j < HD; ++j) s0 *= g[j];
        kv[0] = s0;
        *reinterpret_cast<float4*>(&k_lds[t][0]) = make_float4(kv[0], kv[1], kv[2], kv[3]);
        *reinterpret_cast<float4*>(&k_lds[t][4]) = make_float4(kv[4], kv[5], kv[6], kv[7]);
    }
    __syncthreads();

    // this thread's q row, pre-scaled by (1/sqrt(8))*log2(e) for exp2
    const int qrow = qhalf * 128 + r;
    float qs[HD];
    {
        const float c = 0.35355339059327373f * 1.4426950408889634f;
#pragma unroll
        for (int j = 0; j < HD; ++j) qs[j] = k_lds[qrow][j] * c;
    }

    float l  = 0.f;
    float a0 = 0.f, a1 = 0.f, a2 = 0.f, a3 = 0.f,
          a4 = 0.f, a5 = 0.f, a6 = 0.f, a7 = 0.f;

    const float* kb = &k_lds[khalf * 128][0];
#pragma unroll 4
    for (int kk = 0; kk < 128; ++kk) {
        float4 kv0 = *reinterpret_cast<const float4*>(kb + kk * 8);
        float4 kv1 = *reinterpret_cast<const float4*>(kb + kk * 8 + 4);
        // pairwise tree (explicit association; no fast-math)
        float d01 = fmaf(qs[1], kv0.y, qs[0] * kv0.x);
        float d23 = fmaf(qs[3], kv0.w, qs[2] * kv0.z);
        float d45 = fmaf(qs[5], kv1.y, qs[4] * kv1.x);
        float d67 = fmaf(qs[7], kv1.w, qs[6] * kv1.z);
        float d   = (d01 + d23) + (d45 + d67);
        float p   = exp2f(d);          // = exp(score) since qs pre-scaled
        l += p;
        a0 = fmaf(p, kv0.x, a0); a1 = fmaf(p, kv0.y, a1);
        a2 = fmaf(p, kv0.z, a2); a3 = fmaf(p, kv0.w, a3);
        a4 = fmaf(p, kv1.x, a4); a5 = fmaf(p, kv1.y, a5);
        a6 = fmaf(p, kv1.z, a6); a7 = fmaf(p, kv1.w, a7);
    }

    if (khalf) {
        p_lds[r][0] = l;
        p_lds[r][1] = a0; p_lds[r][2] = a1; p_lds[r][3] = a2; p_lds[r][4] = a3;
        p_lds[r][5] = a4; p_lds[r][6] = a5; p_lds[r][7] = a6; p_lds[r][8] = a7;
    }
    __syncthreads();
    if (!khalf) {
        l  += p_lds[r][0];
        a0 += p_lds[r][1]; a1 += p_lds[r][2]; a2 += p_lds[r][3]; a3 += p_lds[r][4];
        a4 += p_lds[r][5]; a5 += p_lds[r][6]; a6 += p_lds[r][7]; a7 += p_lds[r][8];
        const float inv = 1.0f / l;
        float* yr = att + ((size_t)(b * SEQ + qrow) * EMB + h * HD);
        *reinterpret_cast<float4*>(&yr[0]) = make_float4(a0 * inv, a1 * inv, a2 * inv, a3 * inv);
        *reinterpret_cast<float4*>(&yr[4]) = make_float4(a4 * inv, a5 * inv, a6 * inv, a7 * inv);
    }
}

// ---------------------------------------------------------------------------
// Kernel 2: Y = A @ W^T + bias.  A (1024,256), W (256,256) row-major [n][k].
// BM=BN=32. K staged in TWO 128-wide chunks (transposed, pad +2 => 8B-aligned
// float2 reads) — 34 KB LDS total, under the 64 KB static limit. grid =
// (32, 8) = 256 blocks, 256 threads, 2x2 outputs/thread.
// Inner loop: 2 ds_read_b64 + 4 fma per k.
// ---------------------------------------------------------------------------
#define BM2 32
#define BN2 32
#define BK2 128

__global__ __launch_bounds__(256) void comb_kernel(
    const float* __restrict__ A,
    const float* __restrict__ W,
    const float* __restrict__ bias,
    float* __restrict__ Y)
{
    __shared__ float AsT[BK2][BM2 + 2];   // [k][m], 17 KB
    __shared__ float WsT[BK2][BN2 + 2];   // [k][n], 17 KB

    const int tid  = threadIdx.x;
    const int row0 = blockIdx.x * BM2;
    const int col0 = blockIdx.y * BN2;

    const int tx = tid & 15;   // -> cols col0 + tx*2 + {0,1}
    const int ty = tid >> 4;   // -> rows row0 + ty*2 + {0,1}

    float acc00 = 0.f, acc01 = 0.f, acc10 = 0.f, acc11 = 0.f;

    const int r     = tid >> 3;         // 0..31 (staging row)
    const int cbase = (tid & 7) * 4;    // 0..28

    for (int k0 = 0; k0 < EMB; k0 += BK2) {
        // stage 32 x 128 of A and W, transposed into LDS
        const float* ar = A + (size_t)(row0 + r) * EMB + k0;
        const float* wr = W + (size_t)(col0 + r) * EMB + k0;
#pragma unroll
        for (int i = 0; i < 4; ++i) {
            const int c = cbase + i * 32;
            float4 av = *reinterpret_cast<const float4*>(&ar[c]);
            AsT[c + 0][r] = av.x; AsT[c + 1][r] = av.y;
            AsT[c + 2][r] = av.z; AsT[c + 3][r] = av.w;
            float4 wv = *reinterpret_cast<const float4*>(&wr[c]);
            WsT[c + 0][r] = wv.x; WsT[c + 1][r] = wv.y;
            WsT[c + 2][r] = wv.z; WsT[c + 3][r] = wv.w;
        }
        __syncthreads();

#pragma unroll 8
        for (int k = 0; k < BK2; ++k) {
            float2 a = *reinterpret_cast<const float2*>(&AsT[k][ty * 2]);
            float2 w = *reinterpret_cast<const float2*>(&WsT[k][tx * 2]);
            acc00 = fmaf(a.x, w.x, acc00); acc01 = fmaf(a.x, w.y, acc01);
            acc10 = fmaf(a.y, w.x, acc10); acc11 = fmaf(a.y, w.y, acc11);
        }
        __syncthreads();
    }

    const int colb = col0 + tx * 2;
    float2 bv = *reinterpret_cast<const float2*>(&bias[colb]);
    {
        const int row = row0 + ty * 2;
        *reinterpret_cast<float2*>(&Y[(size_t)row * EMB + colb]) =
            make_float2(acc00 + bv.x, acc01 + bv.y);
        *reinterpret_cast<float2*>(&Y[(size_t)(row + 1) * EMB + colb]) =
            make_float2(acc10 + bv.x, acc11 + bv.y);
    }
}

extern "C" void kernel_launch(void* const* d_in, const int* in_sizes, int n_in,
                              void* d_out, int out_size, void* d_ws, size_t ws_size,
                              hipStream_t stream) {
    const float* x    = (const float*)d_in[0];   // 4*256*256
    const float* qp   = (const float*)d_in[1];   // 8
    const float* w    = (const float*)d_in[2];   // 256*256
    const float* bias = (const float*)d_in[3];   // 256
    float* out = (float*)d_out;                  // 4*256*256
    float* att = (float*)d_ws;                   // 1 MiB scratch, fully rewritten

    qattn_kernel<<<BATCH * HEADS * 2, 256, 0, stream>>>(x, qp, att);
    comb_kernel<<<dim3((BATCH * SEQ) / BM2, EMB / BN2), 256, 0, stream>>>(att, w, bias, out);
}

// Round 5
// 75.654 us; speedup vs baseline: 1.2381x; 1.0447x over previous
//
#include <hip/hip_runtime.h>
#include <math.h>

// Geometry (fixed): x (4,256,256) f32, q_params (8,) f32, w_comb (256,256) f32,
// b_comb (256,) f32 -> out (4,256,256) f32. heads=32, hd=8, seq=256, batch=4.
//
// Quantum layer collapses analytically:
//   g_j = cos(x_j + p_j);  q[0] = g1*...*g7;  q[w>=1] = g0*...*gw
//
// Softmax: |q_d| <= 1 => |score| <= 2.83, exp(s) <= 17, denom <= 256*17 —
// fp32-safe WITHOUT max subtraction; partials combine additively.
//
// Timing model (round-4 counters): fixed harness re-poison cost ~72.5 us
// (268 MB fill at 83% HBM peak + restore dispatches). Controllable kernel
// time ~6.5 us; this round targets qattn wave occupancy (1 -> 2 waves/SIMD).

#define BATCH 4
#define SEQ   256
#define EMB   256
#define HEADS 32
#define HD    8

// ---------------------------------------------------------------------------
// Kernel 1: fused q-compute + attention.
// grid = 256 blocks: blockIdx.x = (b*32+h)*2 + qhalf   (1 block/CU)
// block = 512 threads = 8 waves (2/SIMD): thread t -> q-row qhalf*128+(t&127),
// key-quarter kq = t>>7 (64 keys each). kq is wave-uniform; all inner-loop
// LDS reads are broadcast => conflict-free. Partials combined through LDS.
// ---------------------------------------------------------------------------
__global__ __launch_bounds__(512) void qattn_kernel(
    const float* __restrict__ x,
    const float* __restrict__ qp,
    float* __restrict__ att)   // (4*256, 256) layout [b][s][h*8+d]
{
    const int blk   = blockIdx.x;
    const int qhalf = blk & 1;
    const int bh    = blk >> 1;
    const int b     = bh >> 5;
    const int h     = bh & 31;
    const int t     = threadIdx.x;   // 0..511
    const int r     = t & 127;       // q-row within half
    const int kq    = t >> 7;        // key quarter 0..3 (wave-uniform)

    __shared__ float k_lds[SEQ][HD];        // 8 KiB, all 256 collapsed rows
    __shared__ float p_lds[3][128][12];     // partials (l, a0..a7), 18 KiB
                                            // stride 12 floats = 48 B (16B-aligned)

    // ---- threads 0..255 compute collapsed-circuit row t into LDS ----
    if (t < SEQ) {
        const float* xr = x + ((size_t)(b * SEQ + t) * EMB + h * HD);
        float g[HD];
#pragma unroll
        for (int j = 0; j < HD; ++j) g[j] = cosf(xr[j] + qp[j]);
        float kv[HD];
        float run = g[0];
#pragma unroll
        for (int j = 1; j < HD; ++j) { run *= g[j]; kv[j] = run; }
        float s0 = g[1];
#pragma unroll
        for (int j = 2; j < HD; ++j) s0 *= g[j];
        kv[0] = s0;
        *reinterpret_cast<float4*>(&k_lds[t][0]) = make_float4(kv[0], kv[1], kv[2], kv[3]);
        *reinterpret_cast<float4*>(&k_lds[t][4]) = make_float4(kv[4], kv[5], kv[6], kv[7]);
    }
    __syncthreads();

    // this thread's q row, pre-scaled by (1/sqrt(8))*log2(e) for exp2
    const int qrow = qhalf * 128 + r;
    float qs[HD];
    {
        const float c = 0.35355339059327373f * 1.4426950408889634f;
#pragma unroll
        for (int j = 0; j < HD; ++j) qs[j] = k_lds[qrow][j] * c;
    }

    float l  = 0.f;
    float a0 = 0.f, a1 = 0.f, a2 = 0.f, a3 = 0.f,
          a4 = 0.f, a5 = 0.f, a6 = 0.f, a7 = 0.f;

    const float* kb = &k_lds[kq * 64][0];
#pragma unroll 4
    for (int kk = 0; kk < 64; ++kk) {
        float4 kv0 = *reinterpret_cast<const float4*>(kb + kk * 8);
        float4 kv1 = *reinterpret_cast<const float4*>(kb + kk * 8 + 4);
        // pairwise tree (explicit association; no fast-math)
        float d01 = fmaf(qs[1], kv0.y, qs[0] * kv0.x);
        float d23 = fmaf(qs[3], kv0.w, qs[2] * kv0.z);
        float d45 = fmaf(qs[5], kv1.y, qs[4] * kv1.x);
        float d67 = fmaf(qs[7], kv1.w, qs[6] * kv1.z);
        float d   = (d01 + d23) + (d45 + d67);
        float p   = exp2f(d);          // = exp(score) since qs pre-scaled
        l += p;
        a0 = fmaf(p, kv0.x, a0); a1 = fmaf(p, kv0.y, a1);
        a2 = fmaf(p, kv0.z, a2); a3 = fmaf(p, kv0.w, a3);
        a4 = fmaf(p, kv1.x, a4); a5 = fmaf(p, kv1.y, a5);
        a6 = fmaf(p, kv1.z, a6); a7 = fmaf(p, kv1.w, a7);
    }

    if (kq) {
        float* pr = &p_lds[kq - 1][r][0];
        *reinterpret_cast<float4*>(pr + 0) = make_float4(l,  a0, a1, a2);
        *reinterpret_cast<float4*>(pr + 4) = make_float4(a3, a4, a5, a6);
        pr[8] = a7;
    }
    __syncthreads();
    if (kq == 0) {
#pragma unroll
        for (int qtr = 0; qtr < 3; ++qtr) {
            const float* pr = &p_lds[qtr][r][0];
            float4 v0 = *reinterpret_cast<const float4*>(pr + 0);
            float4 v1 = *reinterpret_cast<const float4*>(pr + 4);
            l  += v0.x;
            a0 += v0.y; a1 += v0.z; a2 += v0.w;
            a3 += v1.x; a4 += v1.y; a5 += v1.z; a6 += v1.w;
            a7 += pr[8];
        }
        const float inv = 1.0f / l;
        float* yr = att + ((size_t)(b * SEQ + qrow) * EMB + h * HD);
        *reinterpret_cast<float4*>(&yr[0]) = make_float4(a0 * inv, a1 * inv, a2 * inv, a3 * inv);
        *reinterpret_cast<float4*>(&yr[4]) = make_float4(a4 * inv, a5 * inv, a6 * inv, a7 * inv);
    }
}

// ---------------------------------------------------------------------------
// Kernel 2: Y = A @ W^T + bias.  A (1024,256), W (256,256) row-major [n][k].
// BM=BN=32. K staged in TWO 128-wide chunks (transposed, pad +2 => 8B-aligned
// float2 reads) — 34 KB LDS. grid = (32, 8) = 256 blocks, 256 threads,
// 2x2 outputs/thread. Inner loop: 2 broadcast ds_read_b64 + 4 fma per k
// (~VALU floor for this op). Unchanged from round 4.
// ---------------------------------------------------------------------------
#define BM2 32
#define BN2 32
#define BK2 128

__global__ __launch_bounds__(256) void comb_kernel(
    const float* __restrict__ A,
    const float* __restrict__ W,
    const float* __restrict__ bias,
    float* __restrict__ Y)
{
    __shared__ float AsT[BK2][BM2 + 2];   // [k][m], 17 KB
    __shared__ float WsT[BK2][BN2 + 2];   // [k][n], 17 KB

    const int tid  = threadIdx.x;
    const int row0 = blockIdx.x * BM2;
    const int col0 = blockIdx.y * BN2;

    const int tx = tid & 15;   // -> cols col0 + tx*2 + {0,1}
    const int ty = tid >> 4;   // -> rows row0 + ty*2 + {0,1}

    float acc00 = 0.f, acc01 = 0.f, acc10 = 0.f, acc11 = 0.f;

    const int r     = tid >> 3;         // 0..31 (staging row)
    const int cbase = (tid & 7) * 4;    // 0..28

    for (int k0 = 0; k0 < EMB; k0 += BK2) {
        // stage 32 x 128 of A and W, transposed into LDS
        const float* ar = A + (size_t)(row0 + r) * EMB + k0;
        const float* wr = W + (size_t)(col0 + r) * EMB + k0;
#pragma unroll
        for (int i = 0; i < 4; ++i) {
            const int c = cbase + i * 32;
            float4 av = *reinterpret_cast<const float4*>(&ar[c]);
            AsT[c + 0][r] = av.x; AsT[c + 1][r] = av.y;
            AsT[c + 2][r] = av.z; AsT[c + 3][r] = av.w;
            float4 wv = *reinterpret_cast<const float4*>(&wr[c]);
            WsT[c + 0][r] = wv.x; WsT[c + 1][r] = wv.y;
            WsT[c + 2][r] = wv.z; WsT[c + 3][r] = wv.w;
        }
        __syncthreads();

#pragma unroll 8
        for (int k = 0; k < BK2; ++k) {
            float2 a = *reinterpret_cast<const float2*>(&AsT[k][ty * 2]);
            float2 w = *reinterpret_cast<const float2*>(&WsT[k][tx * 2]);
            acc00 = fmaf(a.x, w.x, acc00); acc01 = fmaf(a.x, w.y, acc01);
            acc10 = fmaf(a.y, w.x, acc10); acc11 = fmaf(a.y, w.y, acc11);
        }
        __syncthreads();
    }

    const int colb = col0 + tx * 2;
    float2 bv = *reinterpret_cast<const float2*>(&bias[colb]);
    {
        const int row = row0 + ty * 2;
        *reinterpret_cast<float2*>(&Y[(size_t)row * EMB + colb]) =
            make_float2(acc00 + bv.x, acc01 + bv.y);
        *reinterpret_cast<float2*>(&Y[(size_t)(row + 1) * EMB + colb]) =
            make_float2(acc10 + bv.x, acc11 + bv.y);
    }
}

extern "C" void kernel_launch(void* const* d_in, const int* in_sizes, int n_in,
                              void* d_out, int out_size, void* d_ws, size_t ws_size,
                              hipStream_t stream) {
    const float* x    = (const float*)d_in[0];   // 4*256*256
    const float* qp   = (const float*)d_in[1];   // 8
    const float* w    = (const float*)d_in[2];   // 256*256
    const float* bias = (const float*)d_in[3];   // 256
    float* out = (float*)d_out;                  // 4*256*256
    float* att = (float*)d_ws;                   // 1 MiB scratch, fully rewritten

    qattn_kernel<<<BATCH * HEADS * 2, 512, 0, stream>>>(x, qp, att);
    comb_kernel<<<dim3((BATCH * SEQ) / BM2, EMB / BN2), 256, 0, stream>>>(att, w, bias, out);
}

// Round 9
// 73.391 us; speedup vs baseline: 1.2763x; 1.0308x over previous
//
#include <hip/hip_runtime.h>
#include <math.h>

// Geometry (fixed): x (4,256,256) f32, q_params (8,) f32, w_comb (256,256) f32,
// b_comb (256,) f32 -> out (4,256,256) f32. heads=32, hd=8, seq=256, batch=4.
//
// Quantum layer collapses analytically:
//   g_j = cos(x_j + p_j);  q[0] = g1*...*g7;  q[w>=1] = g0*...*gw
//
// Softmax: |q_d| <= 1 => |score| <= 2.83, exp(s) <= 17, denom <= 256*17 —
// fp32-safe WITHOUT max subtraction; partials combine additively.
//
// Timing model (rounds 4/5): fixed harness re-poison cost ~72.5 us (268 MB
// d_ws fill at 83% HBM peak + restores). Controllable ~3.1 us: qattn ~1.9
// (VALU-throughput-bound), comb ~1.0. This round: packed-fp32 (v_pk_fma_f32)
// in both inner loops + raw v_exp_f32, + comb k-pair LDS layout.

#define BATCH 4
#define SEQ   256
#define EMB   256
#define HEADS 32
#define HD    8

typedef float v2f __attribute__((ext_vector_type(2)));
typedef float v4f __attribute__((ext_vector_type(4)));

static __device__ __forceinline__ v2f pk_fma(v2f a, v2f b, v2f c) {
    v2f d;
    asm("v_pk_fma_f32 %0, %1, %2, %3" : "=v"(d) : "v"(a), "v"(b), "v"(c));
    return d;
}
static __device__ __forceinline__ v2f pk_mul(v2f a, v2f b) {
    v2f d;
    asm("v_pk_mul_f32 %0, %1, %2" : "=v"(d) : "v"(a), "v"(b));
    return d;
}

#if __has_builtin(__builtin_amdgcn_exp2f)
#define EXP2(xx) __builtin_amdgcn_exp2f(xx)   // raw v_exp_f32; |arg|<=4.1 safe
#else
#define EXP2(xx) exp2f(xx)
#endif

// ---------------------------------------------------------------------------
// Kernel 1: fused q-compute + attention.
// grid = 256 blocks: blockIdx.x = (b*32+h)*2 + qhalf; block = 512 thr = 8
// waves (2/SIMD). thread t -> q-row qhalf*128+(t&127), key-quarter t>>7.
// Inner loop uses packed fp32: 4 pk (dot) + 4 pk (acc) + exp per key.
// k_lds stride 12 floats (48 B): keeps float4 reads 16B-aligned, cuts the
// staging-write bank conflict from 16-way to 8-way (once; negligible).
// ---------------------------------------------------------------------------
__global__ __launch_bounds__(512) void qattn_kernel(
    const float* __restrict__ x,
    const float* __restrict__ qp,
    float* __restrict__ att)   // (4*256, 256) layout [b][s][h*8+d]
{
    const int blk   = blockIdx.x;
    const int qhalf = blk & 1;
    const int bh    = blk >> 1;
    const int b     = bh >> 5;
    const int h     = bh & 31;
    const int t     = threadIdx.x;   // 0..511
    const int r     = t & 127;       // q-row within half
    const int kq    = t >> 7;        // key quarter 0..3 (wave-uniform)

    __shared__ float k_lds[SEQ][12];        // 12 KiB, stride 48 B
    __shared__ float p_lds[3][128][12];     // partials (l, a0..a7), 18 KiB

    if (t < SEQ) {
        const float* xr = x + ((size_t)(b * SEQ + t) * EMB + h * HD);
        float g[HD];
#pragma unroll
        for (int j = 0; j < HD; ++j) g[j] = cosf(xr[j] + qp[j]);
        float kv[HD];
        float run = g[0];
#pragma unroll
        for (int j = 1; j < HD; ++j) { run *= g[j]; kv[j] = run; }
        float s0 = g[1];
#pragma unroll
        for (int j = 2; j < HD; ++j) s0 *= g[j];
        kv[0] = s0;
        *reinterpret_cast<float4*>(&k_lds[t][0]) = make_float4(kv[0], kv[1], kv[2], kv[3]);
        *reinterpret_cast<float4*>(&k_lds[t][4]) = make_float4(kv[4], kv[5], kv[6], kv[7]);
    }
    __syncthreads();

    // q row, pre-scaled by (1/sqrt(8))*log2(e), as 4 packed pairs
    const int qrow = qhalf * 128 + r;
    v2f q01, q23, q45, q67;
    {
        const float c = 0.35355339059327373f * 1.4426950408889634f;
        float4 qv0 = *reinterpret_cast<const float4*>(&k_lds[qrow][0]);
        float4 qv1 = *reinterpret_cast<const float4*>(&k_lds[qrow][4]);
        q01 = (v2f){qv0.x * c, qv0.y * c};
        q23 = (v2f){qv0.z * c, qv0.w * c};
        q45 = (v2f){qv1.x * c, qv1.y * c};
        q67 = (v2f){qv1.z * c, qv1.w * c};
    }

    float l = 0.f;
    v2f A01 = {0.f, 0.f}, A23 = {0.f, 0.f}, A45 = {0.f, 0.f}, A67 = {0.f, 0.f};

    const float* kb = &k_lds[kq * 64][0];
#pragma unroll 4
    for (int kk = 0; kk < 64; ++kk) {
        float4 kv0 = *reinterpret_cast<const float4*>(kb + kk * 12);
        float4 kv1 = *reinterpret_cast<const float4*>(kb + kk * 12 + 4);
        v2f k01 = (v2f){kv0.x, kv0.y}, k23 = (v2f){kv0.z, kv0.w};
        v2f k45 = (v2f){kv1.x, kv1.y}, k67 = (v2f){kv1.z, kv1.w};
        v2f tt = pk_mul(q01, k01);
        tt = pk_fma(q23, k23, tt);
        tt = pk_fma(q45, k45, tt);
        tt = pk_fma(q67, k67, tt);
        float d = tt.x + tt.y;
        float p = EXP2(d);             // exp(score): qs pre-scaled by log2e
        l += p;
        v2f pp = {p, p};
        A01 = pk_fma(pp, k01, A01);
        A23 = pk_fma(pp, k23, A23);
        A45 = pk_fma(pp, k45, A45);
        A67 = pk_fma(pp, k67, A67);
    }

    if (kq) {
        float* pr = &p_lds[kq - 1][r][0];
        *reinterpret_cast<float4*>(pr + 0) = make_float4(l,     A01.x, A01.y, A23.x);
        *reinterpret_cast<float4*>(pr + 4) = make_float4(A23.y, A45.x, A45.y, A67.x);
        pr[8] = A67.y;
    }
    __syncthreads();
    if (kq == 0) {
        float a0 = A01.x, a1 = A01.y, a2 = A23.x, a3 = A23.y;
        float a4 = A45.x, a5 = A45.y, a6 = A67.x, a7 = A67.y;
#pragma unroll
        for (int qtr = 0; qtr < 3; ++qtr) {
            const float* pr = &p_lds[qtr][r][0];
            float4 v0 = *reinterpret_cast<const float4*>(pr + 0);
            float4 v1 = *reinterpret_cast<const float4*>(pr + 4);
            l  += v0.x;
            a0 += v0.y; a1 += v0.z; a2 += v0.w;
            a3 += v1.x; a4 += v1.y; a5 += v1.z; a6 += v1.w;
            a7 += pr[8];
        }
        const float inv = 1.0f / l;
        float* yr = att + ((size_t)(b * SEQ + qrow) * EMB + h * HD);
        *reinterpret_cast<float4*>(&yr[0]) = make_float4(a0 * inv, a1 * inv, a2 * inv, a3 * inv);
        *reinterpret_cast<float4*>(&yr[4]) = make_float4(a4 * inv, a5 * inv, a6 * inv, a7 * inv);
    }
}

// ---------------------------------------------------------------------------
// Kernel 2: Y = A @ W^T + bias.  A (1024,256), W (256,256) row-major [n][k].
// BM=BN=32, grid (32,8)=256 blocks, 256 threads, 2x2 outputs/thread.
// Full K=256 staged ONCE in k-pair-interleaved layout:
//   buf[k2*64 + (m>>1)*4 + (m&1)*2 + j] = M[m][2*k2+j]
// so per k-PAIR each thread does: 2 ds_read_b128 + 4 v_pk_fma_f32.
// Accumulators hold (even-k sum, odd-k sum); combined at the end.
// LDS = 2 * 128*64*4 B = 64 KB exactly. Staging writes are 8-way-conflicted
// (once, ~free); inner-loop reads are broadcast/2-way (free); addresses
// affine in k2 (no per-iter XOR math).
// ---------------------------------------------------------------------------
__global__ __launch_bounds__(256) void comb_kernel(
    const float* __restrict__ A,
    const float* __restrict__ W,
    const float* __restrict__ bias,
    float* __restrict__ Y)
{
    __shared__ float As2[128 * 64];   // 32 KB
    __shared__ float Ws2[128 * 64];   // 32 KB

    const int tid  = threadIdx.x;
    const int row0 = blockIdx.x * BATCH * HD;           // *32
    const int col0 = blockIdx.y * 32;

    // ---- stage full 32x256 A-tile and W-tile, k-pair interleaved ----
    {
        const int r  = tid >> 3;          // 0..31
        const int cb = (tid & 7) * 4;     // 0..28
        const float* ar = A + (size_t)(row0 + r) * EMB;
        const float* wr = W + (size_t)(col0 + r) * EMB;
        const int mbase = (r >> 1) * 4 + (r & 1) * 2;   // word offset of row r in a k2 row
#pragma unroll
        for (int i = 0; i < 8; ++i) {
            const int c  = cb + i * 32;   // even
            const int k2 = c >> 1;
            float4 av = *reinterpret_cast<const float4*>(&ar[c]);
            *reinterpret_cast<float2*>(&As2[k2 * 64 + mbase])       = make_float2(av.x, av.y);
            *reinterpret_cast<float2*>(&As2[(k2 + 1) * 64 + mbase]) = make_float2(av.z, av.w);
            float4 wv = *reinterpret_cast<const float4*>(&wr[c]);
            *reinterpret_cast<float2*>(&Ws2[k2 * 64 + mbase])       = make_float2(wv.x, wv.y);
            *reinterpret_cast<float2*>(&Ws2[(k2 + 1) * 64 + mbase]) = make_float2(wv.z, wv.w);
        }
    }
    __syncthreads();

    const int tx = tid & 15;   // -> cols col0 + tx*2 + {0,1}
    const int ty = tid >> 4;   // -> rows row0 + ty*2 + {0,1}

    v2f c00 = {0.f, 0.f}, c01 = {0.f, 0.f}, c10 = {0.f, 0.f}, c11 = {0.f, 0.f};

    const float* ab = &As2[ty * 4];
    const float* wb = &Ws2[tx * 4];
#pragma unroll 8
    for (int k2 = 0; k2 < 128; ++k2) {
        v4f a4 = *reinterpret_cast<const v4f*>(ab + k2 * 64);  // (a00,a01,a10,a11)
        v4f w4 = *reinterpret_cast<const v4f*>(wb + k2 * 64);  // (w00,w01,w10,w11)
        c00 = pk_fma(a4.xy, w4.xy, c00);
        c01 = pk_fma(a4.xy, w4.zw, c01);
        c10 = pk_fma(a4.zw, w4.xy, c10);
        c11 = pk_fma(a4.zw, w4.zw, c11);
    }
    __syncthreads();

    const int colb = col0 + tx * 2;
    float2 bv = *reinterpret_cast<const float2*>(&bias[colb]);
    {
        const int row = row0 + ty * 2;
        *reinterpret_cast<float2*>(&Y[(size_t)row * EMB + colb]) =
            make_float2(c00.x + c00.y + bv.x, c01.x + c01.y + bv.y);
        *reinterpret_cast<float2*>(&Y[(size_t)(row + 1) * EMB + colb]) =
            make_float2(c10.x + c10.y + bv.x, c11.x + c11.y + bv.y);
    }
}

extern "C" void kernel_launch(void* const* d_in, const int* in_sizes, int n_in,
                              void* d_out, int out_size, void* d_ws, size_t ws_size,
                              hipStream_t stream) {
    const float* x    = (const float*)d_in[0];   // 4*256*256
    const float* qp   = (const float*)d_in[1];   // 8
    const float* w    = (const float*)d_in[2];   // 256*256
    const float* bias = (const float*)d_in[3];   // 256
    float* out = (float*)d_out;                  // 4*256*256
    float* att = (float*)d_ws;                   // 1 MiB scratch, fully rewritten

    qattn_kernel<<<BATCH * HEADS * 2, 512, 0, stream>>>(x, qp, att);
    comb_kernel<<<dim3((BATCH * SEQ) / 32, EMB / 32), 256, 0, stream>>>(att, w, bias, out);
}